// Round 5
// baseline (571.985 us; speedup 1.0000x reference)
//
#include <hip/hip_runtime.h>

// ---------- types ----------
typedef __attribute__((ext_vector_type(8))) short short8;
typedef __attribute__((ext_vector_type(8))) _Float16 half8;
typedef __attribute__((ext_vector_type(2))) __fp16 fp16x2;
typedef __attribute__((ext_vector_type(4))) float float4v;

__device__ __forceinline__ unsigned short f2bf(float f) {
  union { unsigned int i; float f; } x; x.f = f;
  unsigned int r = x.i + 0x7fffu + ((x.i >> 16) & 1u);  // round-nearest-even
  return (unsigned short)(r >> 16);
}

// ---------- LayerNorm: one block per row of 768 ----------
__global__ void ln_kernel(const float* __restrict__ in, const float* __restrict__ g,
                          const float* __restrict__ b, unsigned short* __restrict__ out) {
  const int row = blockIdx.x, t = threadIdx.x;
  const float* xr = in + (size_t)row * 768;
  float v0 = xr[t], v1 = xr[t + 256], v2 = xr[t + 512];
  float s = v0 + v1 + v2;
  float s2 = v0 * v0 + v1 * v1 + v2 * v2;
  for (int off = 32; off > 0; off >>= 1) {
    s += __shfl_xor(s, off, 64);
    s2 += __shfl_xor(s2, off, 64);
  }
  __shared__ float red[8];
  const int wave = t >> 6, lane = t & 63;
  if (lane == 0) { red[wave] = s; red[wave + 4] = s2; }
  __syncthreads();
  s = red[0] + red[1] + red[2] + red[3];
  s2 = red[4] + red[5] + red[6] + red[7];
  const float mu = s * (1.0f / 768.0f);
  const float var = s2 * (1.0f / 768.0f) - mu * mu;
  const float rstd = rsqrtf(var + 1e-5f);
  unsigned short* orow = out + (size_t)row * 768;
  orow[t]       = f2bf((v0 - mu) * rstd * g[t]       + b[t]);
  orow[t + 256] = f2bf((v1 - mu) * rstd * g[t + 256] + b[t + 256]);
  orow[t + 512] = f2bf((v2 - mu) * rstd * g[t + 512] + b[t + 512]);
}

// ---------- weight transpose+convert: f32 (K,N) -> bf16 (N,K) ----------
__global__ void wtrans_kernel(const float* __restrict__ in, unsigned short* __restrict__ out,
                              int K, int N) {
  __shared__ float tile[32][33];
  const int k0 = blockIdx.y * 32, n0 = blockIdx.x * 32;
  const int tr = threadIdx.x >> 5, tc = threadIdx.x & 31;
#pragma unroll
  for (int i = 0; i < 4; ++i)
    tile[tr + i * 8][tc] = in[(size_t)(k0 + tr + i * 8) * N + n0 + tc];
  __syncthreads();
#pragma unroll
  for (int i = 0; i < 4; ++i)
    out[(size_t)(n0 + tr + i * 8) * K + k0 + tc] = f2bf(tile[tc][tr + i * 8]);
}

// ---------- GEMM core 128x128: 256 threads, global_load_lds staging ----------
__device__ __forceinline__ void gemm128(
    const unsigned short* __restrict__ A, int lda,
    const unsigned short* __restrict__ Bt, int ldb, int K,
    int row0, int col0,
    unsigned short* As, unsigned short* Bs,
    float4v acc[4][4]) {
  const int t = threadIdx.x, lane = t & 63, wave = t >> 6;
  const int quad = lane >> 4, l16 = lane & 15;
  const int wr = wave >> 1, wc = wave & 1;
  const int sr = lane >> 2;
  const int sc = (lane & 3) * 8;
#pragma unroll
  for (int mt = 0; mt < 4; ++mt)
#pragma unroll
    for (int nt = 0; nt < 4; ++nt) acc[mt][nt] = (float4v)(0.0f);

  for (int kk = 0; kk < K; kk += 32) {
    __syncthreads();
#pragma unroll
    for (int j = 0; j < 2; ++j) {
      const int chunk = wave * 2 + j;
      const int r = chunk * 16 + sr;
      __builtin_amdgcn_global_load_lds(
          (const __attribute__((address_space(1))) unsigned int*)(A + (size_t)(row0 + r) * lda + kk + sc),
          (__attribute__((address_space(3))) unsigned int*)(As + chunk * 512),
          16, 0, 0);
      __builtin_amdgcn_global_load_lds(
          (const __attribute__((address_space(1))) unsigned int*)(Bt + (size_t)(col0 + r) * ldb + kk + sc),
          (__attribute__((address_space(3))) unsigned int*)(Bs + chunk * 512),
          16, 0, 0);
    }
    __syncthreads();
    short8 af[4], bfv[4];
#pragma unroll
    for (int i = 0; i < 4; ++i) {
      af[i]  = *(const short8*)(As + (wr * 64 + i * 16 + l16) * 32 + quad * 8);
      bfv[i] = *(const short8*)(Bs + (wc * 64 + i * 16 + l16) * 32 + quad * 8);
    }
#pragma unroll
    for (int mt = 0; mt < 4; ++mt)
#pragma unroll
      for (int nt = 0; nt < 4; ++nt)
        acc[mt][nt] = __builtin_amdgcn_mfma_f32_16x16x32_bf16(af[mt], bfv[nt], acc[mt][nt], 0, 0, 0);
  }
}

#define GEMM128_PROLOGUE                                         \
  __shared__ unsigned short As[128 * 32];                        \
  __shared__ unsigned short Bs[128 * 32];                        \
  float4v acc[4][4];                                             \
  const int col0 = blockIdx.x * 128, row0 = blockIdx.y * 128;    \
  const int t = threadIdx.x, lane = t & 63, wave = t >> 6;       \
  const int quad = lane >> 4, l16 = lane & 15;                   \
  const int wr = wave >> 1, wc = wave & 1; (void)t;

// ---------- GEMM core 128x64: 256 threads (for small-N GEMMs -> 2x grid) ----------
__device__ __forceinline__ void gemm12864(
    const unsigned short* __restrict__ A, int lda,
    const unsigned short* __restrict__ Bt, int ldb, int K,
    int row0, int col0,
    unsigned short* As, unsigned short* Bs,
    float4v acc[2][4]) {
  const int t = threadIdx.x, lane = t & 63, wave = t >> 6;
  const int quad = lane >> 4, l16 = lane & 15;
  const int sr = lane >> 2;
  const int sc = (lane & 3) * 8;
#pragma unroll
  for (int mt = 0; mt < 2; ++mt)
#pragma unroll
    for (int nt = 0; nt < 4; ++nt) acc[mt][nt] = (float4v)(0.0f);

  for (int kk = 0; kk < K; kk += 32) {
    __syncthreads();
#pragma unroll
    for (int j = 0; j < 2; ++j) {
      const int chunk = wave * 2 + j;
      const int r = chunk * 16 + sr;
      __builtin_amdgcn_global_load_lds(
          (const __attribute__((address_space(1))) unsigned int*)(A + (size_t)(row0 + r) * lda + kk + sc),
          (__attribute__((address_space(3))) unsigned int*)(As + chunk * 512),
          16, 0, 0);
    }
    {
      const int r = wave * 16 + sr;
      __builtin_amdgcn_global_load_lds(
          (const __attribute__((address_space(1))) unsigned int*)(Bt + (size_t)(col0 + r) * ldb + kk + sc),
          (__attribute__((address_space(3))) unsigned int*)(Bs + wave * 512),
          16, 0, 0);
    }
    __syncthreads();
    short8 af[2], bfv[4];
#pragma unroll
    for (int i = 0; i < 2; ++i)
      af[i] = *(const short8*)(As + (wave * 32 + i * 16 + l16) * 32 + quad * 8);
#pragma unroll
    for (int i = 0; i < 4; ++i)
      bfv[i] = *(const short8*)(Bs + (i * 16 + l16) * 32 + quad * 8);
#pragma unroll
    for (int mt = 0; mt < 2; ++mt)
#pragma unroll
      for (int nt = 0; nt < 4; ++nt)
        acc[mt][nt] = __builtin_amdgcn_mfma_f32_16x16x32_bf16(af[mt], bfv[nt], acc[mt][nt], 0, 0, 0);
  }
}

#define GEMM12864_PROLOGUE                                       \
  __shared__ unsigned short As[128 * 32];                        \
  __shared__ unsigned short Bs[64 * 32];                         \
  float4v acc[2][4];                                             \
  const int col0 = blockIdx.x * 64, row0 = blockIdx.y * 128;     \
  const int t = threadIdx.x, lane = t & 63, wave = t >> 6;       \
  const int quad = lane >> 4, l16 = lane & 15; (void)t;

// ---------- kv GEMM: xn @ w_kv -> k (B,H,N,DH) f16, v^T (B,H,DH,N) f16 ----------
__global__ void gemm_kv_kernel(const unsigned short* __restrict__ xn,
                               const unsigned short* __restrict__ wkvt,
                               _Float16* __restrict__ kbuf,
                               _Float16* __restrict__ vtbuf) {
  GEMM128_PROLOGUE
  gemm128(xn, 768, wkvt, 768, 768, row0, col0, As, Bs, acc);
#pragma unroll
  for (int mt = 0; mt < 4; ++mt)
#pragma unroll
    for (int nt = 0; nt < 4; ++nt) {
      const int j = col0 + wc * 64 + nt * 16 + l16;
#pragma unroll
      for (int r = 0; r < 4; ++r) {
        const int m = row0 + wr * 64 + mt * 16 + quad * 4 + r;
        const int bb = m >> 10, n = m & 1023;
        const float c = acc[mt][nt][r];
        if (j < 768) {
          const int hh = j >> 6, d = j & 63;
          kbuf[((size_t)(bb * 12 + hh) * 1024 + n) * 64 + d] = (_Float16)c;
        } else {
          const int j2 = j - 768, hh = j2 >> 6, d = j2 & 63;
          vtbuf[((size_t)(bb * 12 + hh) * 64 + d) * 1024 + n] = (_Float16)c;
        }
      }
    }
}

// ---------- MFMA flash attention, f16, no barriers ----------
// Block = (b,h,64 q rows); 4 waves x 16 q rows; key chunks of 64.
// S^T = K·Q^T (operands swapped): lane holds S[key=quad*4+r][q=l16] -> packed b64
// P writes; per-lane scalar (m,l) state; K/V fragments read directly from global
// (kbuf rows & vtbuf rows are exactly the MFMA frag layout). LDS = Ps only (9 KB).
#define PST 72
__global__ void attn_kernel(const float* __restrict__ q_extra,
                            const _Float16* __restrict__ kbuf,
                            const _Float16* __restrict__ vtbuf,
                            unsigned short* __restrict__ ao) {
  __shared__ _Float16 Ps[4][16 * PST];
  const int b = blockIdx.z, h = blockIdx.y, q0 = blockIdx.x * 64;
  const int t = threadIdx.x, lane = t & 63, wave = t >> 6;
  const int quad = lane >> 4, l16 = lane & 15;

  // Q fragments (A-layout) f16, pre-scaled by 1/8
  half8 qf0, qf1;
  {
    const float* qp = q_extra +
        ((size_t)((b * 1024 + q0 + wave * 16 + l16) * 12 + h)) * 64 + quad * 8;
    float4 a0 = *(const float4*)(qp);
    float4 a1 = *(const float4*)(qp + 4);
    float4 c0 = *(const float4*)(qp + 32);
    float4 c1 = *(const float4*)(qp + 36);
    union { fp16x2 h2[4]; half8 h8; } u0, u1;
    u0.h2[0] = __builtin_amdgcn_cvt_pkrtz(a0.x * 0.125f, a0.y * 0.125f);
    u0.h2[1] = __builtin_amdgcn_cvt_pkrtz(a0.z * 0.125f, a0.w * 0.125f);
    u0.h2[2] = __builtin_amdgcn_cvt_pkrtz(a1.x * 0.125f, a1.y * 0.125f);
    u0.h2[3] = __builtin_amdgcn_cvt_pkrtz(a1.z * 0.125f, a1.w * 0.125f);
    u1.h2[0] = __builtin_amdgcn_cvt_pkrtz(c0.x * 0.125f, c0.y * 0.125f);
    u1.h2[1] = __builtin_amdgcn_cvt_pkrtz(c0.z * 0.125f, c0.w * 0.125f);
    u1.h2[2] = __builtin_amdgcn_cvt_pkrtz(c1.x * 0.125f, c1.y * 0.125f);
    u1.h2[3] = __builtin_amdgcn_cvt_pkrtz(c1.z * 0.125f, c1.w * 0.125f);
    qf0 = u0.h8; qf1 = u1.h8;
  }

  const _Float16* kb = kbuf + (size_t)(b * 12 + h) * 65536;
  const _Float16* vb = vtbuf + (size_t)(b * 12 + h) * 65536;
  _Float16* pw = Ps[wave];

  float m_s = -1e30f, l_s = 0.0f;
  float4v acc[4];
  acc[0] = (float4v)(0.f); acc[1] = (float4v)(0.f);
  acc[2] = (float4v)(0.f); acc[3] = (float4v)(0.f);

  for (int c = 0; c < 16; ++c) {
    const int key0 = c * 64;
    // S^T = K @ Q^T : 4 tiles of 16 keys (K frags straight from global)
    float4v s[4];
#pragma unroll
    for (int kt = 0; kt < 4; ++kt) {
      const _Float16* kr = kb + (size_t)(key0 + kt * 16 + l16) * 64;
      half8 kf0 = *(const half8*)(kr + quad * 8);
      half8 kf1 = *(const half8*)(kr + 32 + quad * 8);
      float4v a = (float4v)(0.f);
      a = __builtin_amdgcn_mfma_f32_16x16x32_f16(kf0, qf0, a, 0, 0, 0);
      a = __builtin_amdgcn_mfma_f32_16x16x32_f16(kf1, qf1, a, 0, 0, 0);
      s[kt] = a;
    }

    // per-lane online softmax for q = l16 (16 key-values in-lane, quads via XOR)
    float mx = fmaxf(fmaxf(fmaxf(s[0][0], s[0][1]), fmaxf(s[0][2], s[0][3])),
                     fmaxf(fmaxf(s[1][0], s[1][1]), fmaxf(s[1][2], s[1][3])));
    mx = fmaxf(mx, fmaxf(fmaxf(fmaxf(s[2][0], s[2][1]), fmaxf(s[2][2], s[2][3])),
                         fmaxf(fmaxf(s[3][0], s[3][1]), fmaxf(s[3][2], s[3][3]))));
    mx = fmaxf(mx, __shfl_xor(mx, 16, 64));
    mx = fmaxf(mx, __shfl_xor(mx, 32, 64));
    const float mn = fmaxf(m_s, mx);
    const float alpha = __expf(m_s - mn);
    m_s = mn;

    float sum = 0.0f;
#pragma unroll
    for (int kt = 0; kt < 4; ++kt) {
      const float p0 = __expf(s[kt][0] - mn);
      const float p1 = __expf(s[kt][1] - mn);
      const float p2 = __expf(s[kt][2] - mn);
      const float p3 = __expf(s[kt][3] - mn);
      sum += (p0 + p1) + (p2 + p3);
      union { fp16x2 h2[2]; uint2 u; } pk;
      pk.h2[0] = __builtin_amdgcn_cvt_pkrtz(p0, p1);
      pk.h2[1] = __builtin_amdgcn_cvt_pkrtz(p2, p3);
      *(uint2*)(pw + l16 * PST + kt * 16 + quad * 4) = pk.u;
    }
    sum += __shfl_xor(sum, 16, 64);
    sum += __shfl_xor(sum, 32, 64);
    l_s = l_s * alpha + sum;

    // broadcast alpha to O-row layout (q = quad*4 + r) and rescale O
    float ab[4];
#pragma unroll
    for (int r = 0; r < 4; ++r) ab[r] = __shfl(alpha, quad * 4 + r, 64);
#pragma unroll
    for (int nt = 0; nt < 4; ++nt)
#pragma unroll
      for (int r = 0; r < 4; ++r) acc[nt][r] *= ab[r];

    // O += P @ V (P from per-wave LDS; V^T frags straight from global)
    half8 pf0 = *(const half8*)(pw + l16 * PST + quad * 8);
    half8 pf1 = *(const half8*)(pw + l16 * PST + 32 + quad * 8);
#pragma unroll
    for (int nt = 0; nt < 4; ++nt) {
      const _Float16* vr = vb + (size_t)(nt * 16 + l16) * 1024 + key0;
      half8 vf0 = *(const half8*)(vr + quad * 8);
      half8 vf1 = *(const half8*)(vr + 32 + quad * 8);
      acc[nt] = __builtin_amdgcn_mfma_f32_16x16x32_f16(pf0, vf0, acc[nt], 0, 0, 0);
      acc[nt] = __builtin_amdgcn_mfma_f32_16x16x32_f16(pf1, vf1, acc[nt], 0, 0, 0);
    }
  }

  const float inv = 1.0f / l_s;
  float ib[4];
#pragma unroll
  for (int r = 0; r < 4; ++r) ib[r] = __shfl(inv, quad * 4 + r, 64);
#pragma unroll
  for (int nt = 0; nt < 4; ++nt) {
#pragma unroll
    for (int r = 0; r < 4; ++r) {
      const int m = q0 + wave * 16 + quad * 4 + r;
      ao[(size_t)(b * 1024 + m) * 768 + h * 64 + nt * 16 + l16] =
          f2bf(acc[nt][r] * ib[r]);
    }
  }
}

// ---------- out-proj GEMM + bias + residual -> x2 (f32), 128x64 tiles ----------
__global__ void gemm_outproj_kernel(const unsigned short* __restrict__ ao,
                                    const unsigned short* __restrict__ woutt,
                                    const float* __restrict__ b_out,
                                    const float* __restrict__ x,
                                    float* __restrict__ x2) {
  GEMM12864_PROLOGUE
  gemm12864(ao, 768, woutt, 768, 768, row0, col0, As, Bs, acc);
#pragma unroll
  for (int mt = 0; mt < 2; ++mt)
#pragma unroll
    for (int nt = 0; nt < 4; ++nt) {
      const int j = col0 + nt * 16 + l16;
#pragma unroll
      for (int r = 0; r < 4; ++r) {
        const int m = row0 + wave * 32 + mt * 16 + quad * 4 + r;
        const size_t idx = (size_t)m * 768 + j;
        x2[idx] = acc[mt][nt][r] + b_out[j] + x[idx];
      }
    }
}

// ---------- MLP1 GEMM + bias + exact GELU -> h1 (bf16), 128x128 ----------
__global__ void gemm_mlp1_kernel(const unsigned short* __restrict__ h,
                                 const unsigned short* __restrict__ w1t,
                                 const float* __restrict__ b1,
                                 unsigned short* __restrict__ h1) {
  GEMM128_PROLOGUE
  gemm128(h, 768, w1t, 768, 768, row0, col0, As, Bs, acc);
#pragma unroll
  for (int mt = 0; mt < 4; ++mt)
#pragma unroll
    for (int nt = 0; nt < 4; ++nt) {
      const int j = col0 + wc * 64 + nt * 16 + l16;
#pragma unroll
      for (int r = 0; r < 4; ++r) {
        const int m = row0 + wr * 64 + mt * 16 + quad * 4 + r;
        const float y = acc[mt][nt][r] + b1[j];
        const float ge = 0.5f * y * (1.0f + erff(y * 0.70710678118654752f));
        h1[(size_t)m * 3072 + j] = f2bf(ge);
      }
    }
}

// ---------- MLP2 GEMM + bias + residual -> out (f32), 128x64 tiles ----------
__global__ void gemm_mlp2_kernel(const unsigned short* __restrict__ h1,
                                 const unsigned short* __restrict__ w2t,
                                 const float* __restrict__ b2,
                                 const float* __restrict__ x2,
                                 float* __restrict__ out) {
  GEMM12864_PROLOGUE
  gemm12864(h1, 3072, w2t, 3072, 3072, row0, col0, As, Bs, acc);
#pragma unroll
  for (int mt = 0; mt < 2; ++mt)
#pragma unroll
    for (int nt = 0; nt < 4; ++nt) {
      const int j = col0 + nt * 16 + l16;
#pragma unroll
      for (int r = 0; r < 4; ++r) {
        const int m = row0 + wave * 32 + mt * 16 + quad * 4 + r;
        const size_t idx = (size_t)m * 768 + j;
        out[idx] = acc[mt][nt][r] + b2[j] + x2[idx];
      }
    }
}

// ---------- launch ----------
extern "C" void kernel_launch(void* const* d_in, const int* in_sizes, int n_in,
                              void* d_out, int out_size, void* d_ws, size_t ws_size,
                              hipStream_t stream) {
  const float* x       = (const float*)d_in[0];
  const float* q_extra = (const float*)d_in[1];
  const float* ln1_g   = (const float*)d_in[2];
  const float* ln1_b   = (const float*)d_in[3];
  const float* w_kv    = (const float*)d_in[4];
  const float* w_out   = (const float*)d_in[5];
  const float* b_out   = (const float*)d_in[6];
  const float* ln2_g   = (const float*)d_in[7];
  const float* ln2_b   = (const float*)d_in[8];
  const float* w1      = (const float*)d_in[9];
  const float* b1      = (const float*)d_in[10];
  const float* w2      = (const float*)d_in[11];
  const float* b2      = (const float*)d_in[12];
  float* out = (float*)d_out;

  char* ws = (char*)d_ws;
  unsigned short* xn    = (unsigned short*)(ws);
  _Float16*       kbuf  = (_Float16*)(ws + 12582912);
  _Float16*       vtbuf = (_Float16*)(ws + 25165824);
  unsigned short* ao    = (unsigned short*)(ws + 37748736);
  float*          x2    = (float*)(ws + 50331648);
  unsigned short* h1    = (unsigned short*)(ws + 75497472);
  unsigned short* hbuf  = xn;   // xn dead after kv GEMM
  // transposed bf16 weights in dead regions:
  unsigned short* wkvt  = ao;                          // dead before attn writes ao
  unsigned short* woutt = h1;                          // dead before mlp1 writes h1
  unsigned short* w1t   = (unsigned short*)kbuf;       // kbuf dead after attn
  unsigned short* w2t   = (unsigned short*)vtbuf;      // vtbuf dead after attn

  ln_kernel<<<8192, 256, 0, stream>>>(x, ln1_g, ln1_b, xn);
  wtrans_kernel<<<dim3(48, 24), 256, 0, stream>>>(w_kv, wkvt, 768, 1536);
  wtrans_kernel<<<dim3(24, 24), 256, 0, stream>>>(w_out, woutt, 768, 768);
  gemm_kv_kernel<<<dim3(12, 64), 256, 0, stream>>>(xn, wkvt, kbuf, vtbuf);
  attn_kernel<<<dim3(16, 12, 8), 256, 0, stream>>>(q_extra, kbuf, vtbuf, ao);
  wtrans_kernel<<<dim3(96, 24), 256, 0, stream>>>(w1, w1t, 768, 3072);
  wtrans_kernel<<<dim3(24, 96), 256, 0, stream>>>(w2, w2t, 3072, 768);
  gemm_outproj_kernel<<<dim3(12, 64), 256, 0, stream>>>(ao, woutt, b_out, x, x2);
  ln_kernel<<<8192, 256, 0, stream>>>(x2, ln2_g, ln2_b, hbuf);
  gemm_mlp1_kernel<<<dim3(24, 64), 256, 0, stream>>>(hbuf, w1t, b1, h1);
  gemm_mlp2_kernel<<<dim3(12, 64), 256, 0, stream>>>(h1, w2t, b2, x2, out);
}

// Round 6
// 429.450 us; speedup vs baseline: 1.3319x; 1.3319x over previous
//
#include <hip/hip_runtime.h>

// ---------- types ----------
typedef __attribute__((ext_vector_type(8))) short short8;
typedef __attribute__((ext_vector_type(8))) _Float16 half8;
typedef __attribute__((ext_vector_type(2))) __fp16 fp16x2;
typedef __attribute__((ext_vector_type(4))) float float4v;

__device__ __forceinline__ unsigned short f2bf(float f) {
  union { unsigned int i; float f; } x; x.f = f;
  unsigned int r = x.i + 0x7fffu + ((x.i >> 16) & 1u);  // round-nearest-even
  return (unsigned short)(r >> 16);
}

// ---------- LayerNorm: one block per row of 768 ----------
__global__ void ln_kernel(const float* __restrict__ in, const float* __restrict__ g,
                          const float* __restrict__ b, unsigned short* __restrict__ out) {
  const int row = blockIdx.x, t = threadIdx.x;
  const float* xr = in + (size_t)row * 768;
  float v0 = xr[t], v1 = xr[t + 256], v2 = xr[t + 512];
  float s = v0 + v1 + v2;
  float s2 = v0 * v0 + v1 * v1 + v2 * v2;
  for (int off = 32; off > 0; off >>= 1) {
    s += __shfl_xor(s, off, 64);
    s2 += __shfl_xor(s2, off, 64);
  }
  __shared__ float red[8];
  const int wave = t >> 6, lane = t & 63;
  if (lane == 0) { red[wave] = s; red[wave + 4] = s2; }
  __syncthreads();
  s = red[0] + red[1] + red[2] + red[3];
  s2 = red[4] + red[5] + red[6] + red[7];
  const float mu = s * (1.0f / 768.0f);
  const float var = s2 * (1.0f / 768.0f) - mu * mu;
  const float rstd = rsqrtf(var + 1e-5f);
  unsigned short* orow = out + (size_t)row * 768;
  orow[t]       = f2bf((v0 - mu) * rstd * g[t]       + b[t]);
  orow[t + 256] = f2bf((v1 - mu) * rstd * g[t + 256] + b[t + 256]);
  orow[t + 512] = f2bf((v2 - mu) * rstd * g[t + 512] + b[t + 512]);
}

// ---------- weight transpose+convert: f32 (K,N) -> bf16 (N,K) ----------
__global__ void wtrans_kernel(const float* __restrict__ in, unsigned short* __restrict__ out,
                              int K, int N) {
  __shared__ float tile[32][33];
  const int k0 = blockIdx.y * 32, n0 = blockIdx.x * 32;
  const int tr = threadIdx.x >> 5, tc = threadIdx.x & 31;
#pragma unroll
  for (int i = 0; i < 4; ++i)
    tile[tr + i * 8][tc] = in[(size_t)(k0 + tr + i * 8) * N + n0 + tc];
  __syncthreads();
#pragma unroll
  for (int i = 0; i < 4; ++i)
    out[(size_t)(n0 + tr + i * 8) * K + k0 + tc] = f2bf(tile[tc][tr + i * 8]);
}

// ---------- GEMM core 128x128: 256 threads, global_load_lds staging ----------
__device__ __forceinline__ void gemm128(
    const unsigned short* __restrict__ A, int lda,
    const unsigned short* __restrict__ Bt, int ldb, int K,
    int row0, int col0,
    unsigned short* As, unsigned short* Bs,
    float4v acc[4][4]) {
  const int t = threadIdx.x, lane = t & 63, wave = t >> 6;
  const int quad = lane >> 4, l16 = lane & 15;
  const int wr = wave >> 1, wc = wave & 1;
  const int sr = lane >> 2;
  const int sc = (lane & 3) * 8;
#pragma unroll
  for (int mt = 0; mt < 4; ++mt)
#pragma unroll
    for (int nt = 0; nt < 4; ++nt) acc[mt][nt] = (float4v)(0.0f);

  for (int kk = 0; kk < K; kk += 32) {
    __syncthreads();
#pragma unroll
    for (int j = 0; j < 2; ++j) {
      const int chunk = wave * 2 + j;
      const int r = chunk * 16 + sr;
      __builtin_amdgcn_global_load_lds(
          (const __attribute__((address_space(1))) unsigned int*)(A + (size_t)(row0 + r) * lda + kk + sc),
          (__attribute__((address_space(3))) unsigned int*)(As + chunk * 512),
          16, 0, 0);
      __builtin_amdgcn_global_load_lds(
          (const __attribute__((address_space(1))) unsigned int*)(Bt + (size_t)(col0 + r) * ldb + kk + sc),
          (__attribute__((address_space(3))) unsigned int*)(Bs + chunk * 512),
          16, 0, 0);
    }
    __syncthreads();
    short8 af[4], bfv[4];
#pragma unroll
    for (int i = 0; i < 4; ++i) {
      af[i]  = *(const short8*)(As + (wr * 64 + i * 16 + l16) * 32 + quad * 8);
      bfv[i] = *(const short8*)(Bs + (wc * 64 + i * 16 + l16) * 32 + quad * 8);
    }
#pragma unroll
    for (int mt = 0; mt < 4; ++mt)
#pragma unroll
      for (int nt = 0; nt < 4; ++nt)
        acc[mt][nt] = __builtin_amdgcn_mfma_f32_16x16x32_bf16(af[mt], bfv[nt], acc[mt][nt], 0, 0, 0);
  }
}

#define GEMM128_PROLOGUE                                         \
  __shared__ unsigned short As[128 * 32];                        \
  __shared__ unsigned short Bs[128 * 32];                        \
  float4v acc[4][4];                                             \
  const int col0 = blockIdx.x * 128, row0 = blockIdx.y * 128;    \
  const int t = threadIdx.x, lane = t & 63, wave = t >> 6;       \
  const int quad = lane >> 4, l16 = lane & 15;                   \
  const int wr = wave >> 1, wc = wave & 1; (void)t;

// ---------- GEMM core 128x64: 256 threads (for small-N GEMMs -> 2x grid) ----------
__device__ __forceinline__ void gemm12864(
    const unsigned short* __restrict__ A, int lda,
    const unsigned short* __restrict__ Bt, int ldb, int K,
    int row0, int col0,
    unsigned short* As, unsigned short* Bs,
    float4v acc[2][4]) {
  const int t = threadIdx.x, lane = t & 63, wave = t >> 6;
  const int quad = lane >> 4, l16 = lane & 15;
  const int sr = lane >> 2;
  const int sc = (lane & 3) * 8;
#pragma unroll
  for (int mt = 0; mt < 2; ++mt)
#pragma unroll
    for (int nt = 0; nt < 4; ++nt) acc[mt][nt] = (float4v)(0.0f);

  for (int kk = 0; kk < K; kk += 32) {
    __syncthreads();
#pragma unroll
    for (int j = 0; j < 2; ++j) {
      const int chunk = wave * 2 + j;
      const int r = chunk * 16 + sr;
      __builtin_amdgcn_global_load_lds(
          (const __attribute__((address_space(1))) unsigned int*)(A + (size_t)(row0 + r) * lda + kk + sc),
          (__attribute__((address_space(3))) unsigned int*)(As + chunk * 512),
          16, 0, 0);
    }
    {
      const int r = wave * 16 + sr;
      __builtin_amdgcn_global_load_lds(
          (const __attribute__((address_space(1))) unsigned int*)(Bt + (size_t)(col0 + r) * ldb + kk + sc),
          (__attribute__((address_space(3))) unsigned int*)(Bs + wave * 512),
          16, 0, 0);
    }
    __syncthreads();
    short8 af[2], bfv[4];
#pragma unroll
    for (int i = 0; i < 2; ++i)
      af[i] = *(const short8*)(As + (wave * 32 + i * 16 + l16) * 32 + quad * 8);
#pragma unroll
    for (int i = 0; i < 4; ++i)
      bfv[i] = *(const short8*)(Bs + (i * 16 + l16) * 32 + quad * 8);
#pragma unroll
    for (int mt = 0; mt < 2; ++mt)
#pragma unroll
      for (int nt = 0; nt < 4; ++nt)
        acc[mt][nt] = __builtin_amdgcn_mfma_f32_16x16x32_bf16(af[mt], bfv[nt], acc[mt][nt], 0, 0, 0);
  }
}

#define GEMM12864_PROLOGUE                                       \
  __shared__ unsigned short As[128 * 32];                        \
  __shared__ unsigned short Bs[64 * 32];                         \
  float4v acc[2][4];                                             \
  const int col0 = blockIdx.x * 64, row0 = blockIdx.y * 128;     \
  const int t = threadIdx.x, lane = t & 63, wave = t >> 6;       \
  const int quad = lane >> 4, l16 = lane & 15; (void)t;

// ---------- kv GEMM: xn @ w_kv -> k (B,H,N,DH) f16, v^T (B,H,DH,N) f16 ----------
__global__ void gemm_kv_kernel(const unsigned short* __restrict__ xn,
                               const unsigned short* __restrict__ wkvt,
                               _Float16* __restrict__ kbuf,
                               _Float16* __restrict__ vtbuf) {
  GEMM128_PROLOGUE
  gemm128(xn, 768, wkvt, 768, 768, row0, col0, As, Bs, acc);
#pragma unroll
  for (int mt = 0; mt < 4; ++mt)
#pragma unroll
    for (int nt = 0; nt < 4; ++nt) {
      const int j = col0 + wc * 64 + nt * 16 + l16;
#pragma unroll
      for (int r = 0; r < 4; ++r) {
        const int m = row0 + wr * 64 + mt * 16 + quad * 4 + r;
        const int bb = m >> 10, n = m & 1023;
        const float c = acc[mt][nt][r];
        if (j < 768) {
          const int hh = j >> 6, d = j & 63;
          kbuf[((size_t)(bb * 12 + hh) * 1024 + n) * 64 + d] = (_Float16)c;
        } else {
          const int j2 = j - 768, hh = j2 >> 6, d = j2 & 63;
          vtbuf[((size_t)(bb * 12 + hh) * 64 + d) * 1024 + n] = (_Float16)c;
        }
      }
    }
}

// ---------- MFMA flash attention, f16 ----------
// Block = (b,h,128 q rows); 4 waves, each wave owns q rows {qt*64 + wave*16 .. +16} for qt=0,1.
// Key chunks of 64, K/V cooperatively staged in padded LDS (coalesced global reads),
// register-prefetch of next chunk overlaps global latency with compute.
// S^T = K·Q^T: lane holds S[key=quad*4+r][q=l16] -> packed b64 P writes, per-lane (m,l).
#define AST 72  // padded f16 stride (2-way bank alias only)
#define PST 72
__global__ void attn_kernel(const float* __restrict__ q_extra,
                            const _Float16* __restrict__ kbuf,
                            const _Float16* __restrict__ vtbuf,
                            unsigned short* __restrict__ ao) {
  __shared__ _Float16 Ks[64 * AST];
  __shared__ _Float16 Vs[64 * AST];
  __shared__ _Float16 Ps[4][2][16 * PST];
  const int b = blockIdx.z, h = blockIdx.y, q0 = blockIdx.x * 128;
  const int t = threadIdx.x, lane = t & 63, wave = t >> 6;
  const int quad = lane >> 4, l16 = lane & 15;

  // Q fragments (B-operand layout) f16 for both q-tiles, pre-scaled by 1/8
  half8 qf[2][2];
#pragma unroll
  for (int qt = 0; qt < 2; ++qt) {
    const float* qp = q_extra +
        ((size_t)((b * 1024 + q0 + qt * 64 + wave * 16 + l16) * 12 + h)) * 64 + quad * 8;
    float4 a0 = *(const float4*)(qp);
    float4 a1 = *(const float4*)(qp + 4);
    float4 c0 = *(const float4*)(qp + 32);
    float4 c1 = *(const float4*)(qp + 36);
    union { fp16x2 h2[4]; half8 h8; } u0, u1;
    u0.h2[0] = __builtin_amdgcn_cvt_pkrtz(a0.x * 0.125f, a0.y * 0.125f);
    u0.h2[1] = __builtin_amdgcn_cvt_pkrtz(a0.z * 0.125f, a0.w * 0.125f);
    u0.h2[2] = __builtin_amdgcn_cvt_pkrtz(a1.x * 0.125f, a1.y * 0.125f);
    u0.h2[3] = __builtin_amdgcn_cvt_pkrtz(a1.z * 0.125f, a1.w * 0.125f);
    u1.h2[0] = __builtin_amdgcn_cvt_pkrtz(c0.x * 0.125f, c0.y * 0.125f);
    u1.h2[1] = __builtin_amdgcn_cvt_pkrtz(c0.z * 0.125f, c0.w * 0.125f);
    u1.h2[2] = __builtin_amdgcn_cvt_pkrtz(c1.x * 0.125f, c1.y * 0.125f);
    u1.h2[3] = __builtin_amdgcn_cvt_pkrtz(c1.z * 0.125f, c1.w * 0.125f);
    qf[qt][0] = u0.h8; qf[qt][1] = u1.h8;
  }

  const _Float16* kb = kbuf + (size_t)(b * 12 + h) * 65536;
  const _Float16* vb = vtbuf + (size_t)(b * 12 + h) * 65536;
  const int srow = t >> 2, su = (t & 3) * 16;  // staging: row, 32B segment

  // prefetch chunk 0 into registers
  half8 kp0 = *(const half8*)(kb + (size_t)srow * 64 + su);
  half8 kp1 = *(const half8*)(kb + (size_t)srow * 64 + su + 8);
  half8 vp0 = *(const half8*)(vb + (size_t)srow * 1024 + su);
  half8 vp1 = *(const half8*)(vb + (size_t)srow * 1024 + su + 8);

  float m_s[2] = {-1e30f, -1e30f}, l_s[2] = {0.f, 0.f};
  float4v acc[2][4];
#pragma unroll
  for (int qt = 0; qt < 2; ++qt)
#pragma unroll
    for (int nt = 0; nt < 4; ++nt) acc[qt][nt] = (float4v)(0.f);

  for (int c = 0; c < 16; ++c) {
    __syncthreads();  // previous chunk's consumers done
    *(half8*)(Ks + srow * AST + su)     = kp0;
    *(half8*)(Ks + srow * AST + su + 8) = kp1;
    *(half8*)(Vs + srow * AST + su)     = vp0;
    *(half8*)(Vs + srow * AST + su + 8) = vp1;
    if (c < 15) {  // prefetch next chunk (VGPR loads; latency hidden by compute)
      const int key1 = (c + 1) * 64;
      kp0 = *(const half8*)(kb + (size_t)(key1 + srow) * 64 + su);
      kp1 = *(const half8*)(kb + (size_t)(key1 + srow) * 64 + su + 8);
      vp0 = *(const half8*)(vb + (size_t)srow * 1024 + key1 + su);
      vp1 = *(const half8*)(vb + (size_t)srow * 1024 + key1 + su + 8);
    }
    __syncthreads();  // staged tile visible

    // S^T = K @ Q^T for both q-tiles (K frags shared)
    float4v s[2][4];
#pragma unroll
    for (int kt = 0; kt < 4; ++kt) {
      const _Float16* kr = Ks + (kt * 16 + l16) * AST;
      half8 kf0 = *(const half8*)(kr + quad * 8);
      half8 kf1 = *(const half8*)(kr + 32 + quad * 8);
#pragma unroll
      for (int qt = 0; qt < 2; ++qt) {
        float4v a = (float4v)(0.f);
        a = __builtin_amdgcn_mfma_f32_16x16x32_f16(kf0, qf[qt][0], a, 0, 0, 0);
        a = __builtin_amdgcn_mfma_f32_16x16x32_f16(kf1, qf[qt][1], a, 0, 0, 0);
        s[qt][kt] = a;
      }
    }

    // online softmax per q-tile; P -> per-wave LDS (packed b64 writes)
    float ab[2][4];
#pragma unroll
    for (int qt = 0; qt < 2; ++qt) {
      float mx = fmaxf(fmaxf(fmaxf(s[qt][0][0], s[qt][0][1]), fmaxf(s[qt][0][2], s[qt][0][3])),
                       fmaxf(fmaxf(s[qt][1][0], s[qt][1][1]), fmaxf(s[qt][1][2], s[qt][1][3])));
      mx = fmaxf(mx, fmaxf(fmaxf(fmaxf(s[qt][2][0], s[qt][2][1]), fmaxf(s[qt][2][2], s[qt][2][3])),
                           fmaxf(fmaxf(s[qt][3][0], s[qt][3][1]), fmaxf(s[qt][3][2], s[qt][3][3]))));
      mx = fmaxf(mx, __shfl_xor(mx, 16, 64));
      mx = fmaxf(mx, __shfl_xor(mx, 32, 64));
      const float mn = fmaxf(m_s[qt], mx);
      const float alpha = __expf(m_s[qt] - mn);
      m_s[qt] = mn;
      _Float16* pw = Ps[wave][qt];
      float sum = 0.0f;
#pragma unroll
      for (int kt = 0; kt < 4; ++kt) {
        const float p0 = __expf(s[qt][kt][0] - mn);
        const float p1 = __expf(s[qt][kt][1] - mn);
        const float p2 = __expf(s[qt][kt][2] - mn);
        const float p3 = __expf(s[qt][kt][3] - mn);
        sum += (p0 + p1) + (p2 + p3);
        union { fp16x2 h2[2]; uint2 u; } pk;
        pk.h2[0] = __builtin_amdgcn_cvt_pkrtz(p0, p1);
        pk.h2[1] = __builtin_amdgcn_cvt_pkrtz(p2, p3);
        *(uint2*)(pw + l16 * PST + kt * 16 + quad * 4) = pk.u;
      }
      sum += __shfl_xor(sum, 16, 64);
      sum += __shfl_xor(sum, 32, 64);
      l_s[qt] = l_s[qt] * alpha + sum;
#pragma unroll
      for (int r = 0; r < 4; ++r) ab[qt][r] = __shfl(alpha, quad * 4 + r, 64);
#pragma unroll
      for (int nt = 0; nt < 4; ++nt)
#pragma unroll
        for (int r = 0; r < 4; ++r) acc[qt][nt][r] *= ab[qt][r];
    }

    // O += P @ V (V frags shared across q-tiles)
    half8 pf[2][2];
#pragma unroll
    for (int qt = 0; qt < 2; ++qt) {
      const _Float16* pw = Ps[wave][qt];
      pf[qt][0] = *(const half8*)(pw + l16 * PST + quad * 8);
      pf[qt][1] = *(const half8*)(pw + l16 * PST + 32 + quad * 8);
    }
#pragma unroll
    for (int nt = 0; nt < 4; ++nt) {
      const _Float16* vr = Vs + (nt * 16 + l16) * AST;
      half8 vf0 = *(const half8*)(vr + quad * 8);
      half8 vf1 = *(const half8*)(vr + 32 + quad * 8);
#pragma unroll
      for (int qt = 0; qt < 2; ++qt) {
        acc[qt][nt] = __builtin_amdgcn_mfma_f32_16x16x32_f16(pf[qt][0], vf0, acc[qt][nt], 0, 0, 0);
        acc[qt][nt] = __builtin_amdgcn_mfma_f32_16x16x32_f16(pf[qt][1], vf1, acc[qt][nt], 0, 0, 0);
      }
    }
  }

#pragma unroll
  for (int qt = 0; qt < 2; ++qt) {
    const float inv = 1.0f / l_s[qt];
    float ib[4];
#pragma unroll
    for (int r = 0; r < 4; ++r) ib[r] = __shfl(inv, quad * 4 + r, 64);
#pragma unroll
    for (int nt = 0; nt < 4; ++nt) {
#pragma unroll
      for (int r = 0; r < 4; ++r) {
        const int m = q0 + qt * 64 + wave * 16 + quad * 4 + r;
        ao[(size_t)(b * 1024 + m) * 768 + h * 64 + nt * 16 + l16] =
            f2bf(acc[qt][nt][r] * ib[r]);
      }
    }
  }
}

// ---------- out-proj GEMM + bias + residual -> x2 (f32), 128x64 tiles ----------
__global__ void gemm_outproj_kernel(const unsigned short* __restrict__ ao,
                                    const unsigned short* __restrict__ woutt,
                                    const float* __restrict__ b_out,
                                    const float* __restrict__ x,
                                    float* __restrict__ x2) {
  GEMM12864_PROLOGUE
  gemm12864(ao, 768, woutt, 768, 768, row0, col0, As, Bs, acc);
#pragma unroll
  for (int mt = 0; mt < 2; ++mt)
#pragma unroll
    for (int nt = 0; nt < 4; ++nt) {
      const int j = col0 + nt * 16 + l16;
#pragma unroll
      for (int r = 0; r < 4; ++r) {
        const int m = row0 + wave * 32 + mt * 16 + quad * 4 + r;
        const size_t idx = (size_t)m * 768 + j;
        x2[idx] = acc[mt][nt][r] + b_out[j] + x[idx];
      }
    }
}

// ---------- MLP1 GEMM + bias + exact GELU -> h1 (bf16), 128x128 ----------
__global__ void gemm_mlp1_kernel(const unsigned short* __restrict__ h,
                                 const unsigned short* __restrict__ w1t,
                                 const float* __restrict__ b1,
                                 unsigned short* __restrict__ h1) {
  GEMM128_PROLOGUE
  gemm128(h, 768, w1t, 768, 768, row0, col0, As, Bs, acc);
#pragma unroll
  for (int mt = 0; mt < 4; ++mt)
#pragma unroll
    for (int nt = 0; nt < 4; ++nt) {
      const int j = col0 + wc * 64 + nt * 16 + l16;
#pragma unroll
      for (int r = 0; r < 4; ++r) {
        const int m = row0 + wr * 64 + mt * 16 + quad * 4 + r;
        const float y = acc[mt][nt][r] + b1[j];
        const float ge = 0.5f * y * (1.0f + erff(y * 0.70710678118654752f));
        h1[(size_t)m * 3072 + j] = f2bf(ge);
      }
    }
}

// ---------- MLP2 GEMM + bias + residual -> out (f32), 128x64 tiles ----------
__global__ void gemm_mlp2_kernel(const unsigned short* __restrict__ h1,
                                 const unsigned short* __restrict__ w2t,
                                 const float* __restrict__ b2,
                                 const float* __restrict__ x2,
                                 float* __restrict__ out) {
  GEMM12864_PROLOGUE
  gemm12864(h1, 3072, w2t, 3072, 3072, row0, col0, As, Bs, acc);
#pragma unroll
  for (int mt = 0; mt < 2; ++mt)
#pragma unroll
    for (int nt = 0; nt < 4; ++nt) {
      const int j = col0 + nt * 16 + l16;
#pragma unroll
      for (int r = 0; r < 4; ++r) {
        const int m = row0 + wave * 32 + mt * 16 + quad * 4 + r;
        const size_t idx = (size_t)m * 768 + j;
        out[idx] = acc[mt][nt][r] + b2[j] + x2[idx];
      }
    }
}

// ---------- launch ----------
extern "C" void kernel_launch(void* const* d_in, const int* in_sizes, int n_in,
                              void* d_out, int out_size, void* d_ws, size_t ws_size,
                              hipStream_t stream) {
  const float* x       = (const float*)d_in[0];
  const float* q_extra = (const float*)d_in[1];
  const float* ln1_g   = (const float*)d_in[2];
  const float* ln1_b   = (const float*)d_in[3];
  const float* w_kv    = (const float*)d_in[4];
  const float* w_out   = (const float*)d_in[5];
  const float* b_out   = (const float*)d_in[6];
  const float* ln2_g   = (const float*)d_in[7];
  const float* ln2_b   = (const float*)d_in[8];
  const float* w1      = (const float*)d_in[9];
  const float* b1      = (const float*)d_in[10];
  const float* w2      = (const float*)d_in[11];
  const float* b2      = (const float*)d_in[12];
  float* out = (float*)d_out;

  char* ws = (char*)d_ws;
  unsigned short* xn    = (unsigned short*)(ws);
  _Float16*       kbuf  = (_Float16*)(ws + 12582912);
  _Float16*       vtbuf = (_Float16*)(ws + 25165824);
  unsigned short* ao    = (unsigned short*)(ws + 37748736);
  float*          x2    = (float*)(ws + 50331648);
  unsigned short* h1    = (unsigned short*)(ws + 75497472);
  unsigned short* hbuf  = xn;   // xn dead after kv GEMM
  // transposed bf16 weights in dead regions:
  unsigned short* wkvt  = ao;                          // dead before attn writes ao
  unsigned short* woutt = h1;                          // dead before mlp1 writes h1
  unsigned short* w1t   = (unsigned short*)kbuf;       // kbuf dead after attn
  unsigned short* w2t   = (unsigned short*)vtbuf;      // vtbuf dead after attn

  ln_kernel<<<8192, 256, 0, stream>>>(x, ln1_g, ln1_b, xn);
  wtrans_kernel<<<dim3(48, 24), 256, 0, stream>>>(w_kv, wkvt, 768, 1536);
  wtrans_kernel<<<dim3(24, 24), 256, 0, stream>>>(w_out, woutt, 768, 768);
  gemm_kv_kernel<<<dim3(12, 64), 256, 0, stream>>>(xn, wkvt, kbuf, vtbuf);
  attn_kernel<<<dim3(8, 12, 8), 256, 0, stream>>>(q_extra, kbuf, vtbuf, ao);
  wtrans_kernel<<<dim3(96, 24), 256, 0, stream>>>(w1, w1t, 768, 3072);
  wtrans_kernel<<<dim3(24, 96), 256, 0, stream>>>(w2, w2t, 3072, 768);
  gemm_outproj_kernel<<<dim3(12, 64), 256, 0, stream>>>(ao, woutt, b_out, x, x2);
  ln_kernel<<<8192, 256, 0, stream>>>(x2, ln2_g, ln2_b, hbuf);
  gemm_mlp1_kernel<<<dim3(24, 64), 256, 0, stream>>>(hbuf, w1t, b1, h1);
  gemm_mlp2_kernel<<<dim3(12, 64), 256, 0, stream>>>(h1, w2t, b2, x2, out);
}

// Round 7
// 389.665 us; speedup vs baseline: 1.4679x; 1.1021x over previous
//
#include <hip/hip_runtime.h>

// ---------- types ----------
typedef __attribute__((ext_vector_type(8))) short short8;
typedef __attribute__((ext_vector_type(8))) _Float16 half8;
typedef __attribute__((ext_vector_type(2))) __fp16 fp16x2;
typedef __attribute__((ext_vector_type(4))) float float4v;

__device__ __forceinline__ unsigned short f2bf(float f) {
  union { unsigned int i; float f; } x; x.f = f;
  unsigned int r = x.i + 0x7fffu + ((x.i >> 16) & 1u);  // round-nearest-even
  return (unsigned short)(r >> 16);
}

// ---------- LayerNorm: one block per row of 768 ----------
__global__ void ln_kernel(const float* __restrict__ in, const float* __restrict__ g,
                          const float* __restrict__ b, unsigned short* __restrict__ out) {
  const int row = blockIdx.x, t = threadIdx.x;
  const float* xr = in + (size_t)row * 768;
  float v0 = xr[t], v1 = xr[t + 256], v2 = xr[t + 512];
  float s = v0 + v1 + v2;
  float s2 = v0 * v0 + v1 * v1 + v2 * v2;
  for (int off = 32; off > 0; off >>= 1) {
    s += __shfl_xor(s, off, 64);
    s2 += __shfl_xor(s2, off, 64);
  }
  __shared__ float red[8];
  const int wave = t >> 6, lane = t & 63;
  if (lane == 0) { red[wave] = s; red[wave + 4] = s2; }
  __syncthreads();
  s = red[0] + red[1] + red[2] + red[3];
  s2 = red[4] + red[5] + red[6] + red[7];
  const float mu = s * (1.0f / 768.0f);
  const float var = s2 * (1.0f / 768.0f) - mu * mu;
  const float rstd = rsqrtf(var + 1e-5f);
  unsigned short* orow = out + (size_t)row * 768;
  orow[t]       = f2bf((v0 - mu) * rstd * g[t]       + b[t]);
  orow[t + 256] = f2bf((v1 - mu) * rstd * g[t + 256] + b[t + 256]);
  orow[t + 512] = f2bf((v2 - mu) * rstd * g[t + 512] + b[t + 512]);
}

// ---------- weight transpose+convert: f32 (K,N) -> bf16 (N,K) ----------
__global__ void wtrans_kernel(const float* __restrict__ in, unsigned short* __restrict__ out,
                              int K, int N) {
  __shared__ float tile[32][33];
  const int k0 = blockIdx.y * 32, n0 = blockIdx.x * 32;
  const int tr = threadIdx.x >> 5, tc = threadIdx.x & 31;
#pragma unroll
  for (int i = 0; i < 4; ++i)
    tile[tr + i * 8][tc] = in[(size_t)(k0 + tr + i * 8) * N + n0 + tc];
  __syncthreads();
#pragma unroll
  for (int i = 0; i < 4; ++i)
    out[(size_t)(n0 + tr + i * 8) * K + k0 + tc] = f2bf(tile[tc][tr + i * 8]);
}

// ---------- XCD-aware block swizzle ----------
// 1D grid; blocks id%8 land on the same XCD (round-robin heuristic). Assign each
// XCD whole row-stripes so the 'GX' col-blocks of a stripe share one L2.
#define SWIZ_BLOCK(GX, TW)                                        \
  const int _id = (int)blockIdx.x;                                \
  const int _gy8 = (int)gridDim.x / (8 * (GX));                   \
  const int _xcd = _id & 7, _jj = _id >> 3;                       \
  const int row0 = (_xcd * _gy8 + _jj / (GX)) * 128;              \
  const int col0 = (_jj % (GX)) * (TW);

// ---------- GEMM core 128x128, BK=64, XOR-swizzled LDS ----------
// LDS tile [row][64] bf16 (128B row). Granule g (16B) of row r holds global
// granule g^(r&7): glds dest stays linear (base+lane*16), source col permuted;
// fragment ds_read_b128 becomes <=2-way bank aliased (free).
__device__ __forceinline__ void gemm128(
    const unsigned short* __restrict__ A, int lda,
    const unsigned short* __restrict__ Bt, int ldb, int K,
    int row0, int col0,
    unsigned short* As, unsigned short* Bs,
    float4v acc[4][4]) {
  const int t = threadIdx.x, lane = t & 63, wave = t >> 6;
  const int quad = lane >> 4, l16 = lane & 15;
  const int wr = wave >> 1, wc = wave & 1;
  const int srow = lane >> 3;                 // row within 8-row chunk
  const int scol = ((lane & 7) ^ srow) * 8;   // swizzled source column (elems)
#pragma unroll
  for (int mt = 0; mt < 4; ++mt)
#pragma unroll
    for (int nt = 0; nt < 4; ++nt) acc[mt][nt] = (float4v)(0.0f);

  for (int kk = 0; kk < K; kk += 64) {
    __syncthreads();
#pragma unroll
    for (int j = 0; j < 4; ++j) {
      const int chunk = wave * 4 + j;         // 0..15, 8 rows each
      const int r = chunk * 8 + srow;
      __builtin_amdgcn_global_load_lds(
          (const __attribute__((address_space(1))) unsigned int*)(A + (size_t)(row0 + r) * lda + kk + scol),
          (__attribute__((address_space(3))) unsigned int*)(As + chunk * 512),
          16, 0, 0);
      __builtin_amdgcn_global_load_lds(
          (const __attribute__((address_space(1))) unsigned int*)(Bt + (size_t)(col0 + r) * ldb + kk + scol),
          (__attribute__((address_space(3))) unsigned int*)(Bs + chunk * 512),
          16, 0, 0);
    }
    __syncthreads();
#pragma unroll
    for (int ks = 0; ks < 2; ++ks) {
      const int gsw = ((ks * 4 + quad) ^ (l16 & 7)) * 8;
      short8 af[4], bfv[4];
#pragma unroll
      for (int i = 0; i < 4; ++i) {
        af[i]  = *(const short8*)(As + (wr * 64 + i * 16 + l16) * 64 + gsw);
        bfv[i] = *(const short8*)(Bs + (wc * 64 + i * 16 + l16) * 64 + gsw);
      }
#pragma unroll
      for (int mt = 0; mt < 4; ++mt)
#pragma unroll
        for (int nt = 0; nt < 4; ++nt)
          acc[mt][nt] = __builtin_amdgcn_mfma_f32_16x16x32_bf16(af[mt], bfv[nt], acc[mt][nt], 0, 0, 0);
    }
  }
}

#define GEMM128_PROLOGUE(GX)                                     \
  __shared__ unsigned short As[128 * 64];                        \
  __shared__ unsigned short Bs[128 * 64];                        \
  float4v acc[4][4];                                             \
  SWIZ_BLOCK(GX, 128)                                            \
  const int t = threadIdx.x, lane = t & 63, wave = t >> 6;       \
  const int quad = lane >> 4, l16 = lane & 15;                   \
  const int wr = wave >> 1, wc = wave & 1; (void)t;

// ---------- GEMM core 128x64, BK=64, XOR-swizzled LDS ----------
__device__ __forceinline__ void gemm12864(
    const unsigned short* __restrict__ A, int lda,
    const unsigned short* __restrict__ Bt, int ldb, int K,
    int row0, int col0,
    unsigned short* As, unsigned short* Bs,
    float4v acc[2][4]) {
  const int t = threadIdx.x, lane = t & 63, wave = t >> 6;
  const int quad = lane >> 4, l16 = lane & 15;
  const int srow = lane >> 3;
  const int scol = ((lane & 7) ^ srow) * 8;
#pragma unroll
  for (int mt = 0; mt < 2; ++mt)
#pragma unroll
    for (int nt = 0; nt < 4; ++nt) acc[mt][nt] = (float4v)(0.0f);

  for (int kk = 0; kk < K; kk += 64) {
    __syncthreads();
#pragma unroll
    for (int j = 0; j < 4; ++j) {
      const int chunk = wave * 4 + j;
      const int r = chunk * 8 + srow;
      __builtin_amdgcn_global_load_lds(
          (const __attribute__((address_space(1))) unsigned int*)(A + (size_t)(row0 + r) * lda + kk + scol),
          (__attribute__((address_space(3))) unsigned int*)(As + chunk * 512),
          16, 0, 0);
    }
#pragma unroll
    for (int j = 0; j < 2; ++j) {
      const int chunk = wave * 2 + j;          // 0..7
      const int r = chunk * 8 + srow;
      __builtin_amdgcn_global_load_lds(
          (const __attribute__((address_space(1))) unsigned int*)(Bt + (size_t)(col0 + r) * ldb + kk + scol),
          (__attribute__((address_space(3))) unsigned int*)(Bs + chunk * 512),
          16, 0, 0);
    }
    __syncthreads();
#pragma unroll
    for (int ks = 0; ks < 2; ++ks) {
      const int gsw = ((ks * 4 + quad) ^ (l16 & 7)) * 8;
      short8 af[2], bfv[4];
#pragma unroll
      for (int i = 0; i < 2; ++i)
        af[i] = *(const short8*)(As + (wave * 32 + i * 16 + l16) * 64 + gsw);
#pragma unroll
      for (int i = 0; i < 4; ++i)
        bfv[i] = *(const short8*)(Bs + (i * 16 + l16) * 64 + gsw);
#pragma unroll
      for (int mt = 0; mt < 2; ++mt)
#pragma unroll
        for (int nt = 0; nt < 4; ++nt)
          acc[mt][nt] = __builtin_amdgcn_mfma_f32_16x16x32_bf16(af[mt], bfv[nt], acc[mt][nt], 0, 0, 0);
    }
  }
}

#define GEMM12864_PROLOGUE(GX)                                   \
  __shared__ unsigned short As[128 * 64];                        \
  __shared__ unsigned short Bs[64 * 64];                         \
  float4v acc[2][4];                                             \
  SWIZ_BLOCK(GX, 64)                                             \
  const int t = threadIdx.x, lane = t & 63, wave = t >> 6;       \
  const int quad = lane >> 4, l16 = lane & 15; (void)t;

// ---------- kv GEMM: xn @ w_kv -> k (B,H,N,DH) f16, v^T (B,H,DH,N) f16 ----------
__global__ void gemm_kv_kernel(const unsigned short* __restrict__ xn,
                               const unsigned short* __restrict__ wkvt,
                               _Float16* __restrict__ kbuf,
                               _Float16* __restrict__ vtbuf) {
  GEMM128_PROLOGUE(12)
  gemm128(xn, 768, wkvt, 768, 768, row0, col0, As, Bs, acc);
#pragma unroll
  for (int mt = 0; mt < 4; ++mt)
#pragma unroll
    for (int nt = 0; nt < 4; ++nt) {
      const int j = col0 + wc * 64 + nt * 16 + l16;
#pragma unroll
      for (int r = 0; r < 4; ++r) {
        const int m = row0 + wr * 64 + mt * 16 + quad * 4 + r;
        const int bb = m >> 10, n = m & 1023;
        const float c = acc[mt][nt][r];
        if (j < 768) {
          const int hh = j >> 6, d = j & 63;
          kbuf[((size_t)(bb * 12 + hh) * 1024 + n) * 64 + d] = (_Float16)c;
        } else {
          const int j2 = j - 768, hh = j2 >> 6, d = j2 & 63;
          vtbuf[((size_t)(bb * 12 + hh) * 64 + d) * 1024 + n] = (_Float16)c;
        }
      }
    }
}

// ---------- MFMA flash attention, f16 (unchanged from round 6) ----------
#define AST 72
#define PST 72
__global__ void attn_kernel(const float* __restrict__ q_extra,
                            const _Float16* __restrict__ kbuf,
                            const _Float16* __restrict__ vtbuf,
                            unsigned short* __restrict__ ao) {
  __shared__ _Float16 Ks[64 * AST];
  __shared__ _Float16 Vs[64 * AST];
  __shared__ _Float16 Ps[4][2][16 * PST];
  const int b = blockIdx.z, h = blockIdx.y, q0 = blockIdx.x * 128;
  const int t = threadIdx.x, lane = t & 63, wave = t >> 6;
  const int quad = lane >> 4, l16 = lane & 15;

  half8 qf[2][2];
#pragma unroll
  for (int qt = 0; qt < 2; ++qt) {
    const float* qp = q_extra +
        ((size_t)((b * 1024 + q0 + qt * 64 + wave * 16 + l16) * 12 + h)) * 64 + quad * 8;
    float4 a0 = *(const float4*)(qp);
    float4 a1 = *(const float4*)(qp + 4);
    float4 c0 = *(const float4*)(qp + 32);
    float4 c1 = *(const float4*)(qp + 36);
    union { fp16x2 h2[4]; half8 h8; } u0, u1;
    u0.h2[0] = __builtin_amdgcn_cvt_pkrtz(a0.x * 0.125f, a0.y * 0.125f);
    u0.h2[1] = __builtin_amdgcn_cvt_pkrtz(a0.z * 0.125f, a0.w * 0.125f);
    u0.h2[2] = __builtin_amdgcn_cvt_pkrtz(a1.x * 0.125f, a1.y * 0.125f);
    u0.h2[3] = __builtin_amdgcn_cvt_pkrtz(a1.z * 0.125f, a1.w * 0.125f);
    u1.h2[0] = __builtin_amdgcn_cvt_pkrtz(c0.x * 0.125f, c0.y * 0.125f);
    u1.h2[1] = __builtin_amdgcn_cvt_pkrtz(c0.z * 0.125f, c0.w * 0.125f);
    u1.h2[2] = __builtin_amdgcn_cvt_pkrtz(c1.x * 0.125f, c1.y * 0.125f);
    u1.h2[3] = __builtin_amdgcn_cvt_pkrtz(c1.z * 0.125f, c1.w * 0.125f);
    qf[qt][0] = u0.h8; qf[qt][1] = u1.h8;
  }

  const _Float16* kb = kbuf + (size_t)(b * 12 + h) * 65536;
  const _Float16* vb = vtbuf + (size_t)(b * 12 + h) * 65536;
  const int srow = t >> 2, su = (t & 3) * 16;

  half8 kp0 = *(const half8*)(kb + (size_t)srow * 64 + su);
  half8 kp1 = *(const half8*)(kb + (size_t)srow * 64 + su + 8);
  half8 vp0 = *(const half8*)(vb + (size_t)srow * 1024 + su);
  half8 vp1 = *(const half8*)(vb + (size_t)srow * 1024 + su + 8);

  float m_s[2] = {-1e30f, -1e30f}, l_s[2] = {0.f, 0.f};
  float4v acc[2][4];
#pragma unroll
  for (int qt = 0; qt < 2; ++qt)
#pragma unroll
    for (int nt = 0; nt < 4; ++nt) acc[qt][nt] = (float4v)(0.f);

  for (int c = 0; c < 16; ++c) {
    __syncthreads();
    *(half8*)(Ks + srow * AST + su)     = kp0;
    *(half8*)(Ks + srow * AST + su + 8) = kp1;
    *(half8*)(Vs + srow * AST + su)     = vp0;
    *(half8*)(Vs + srow * AST + su + 8) = vp1;
    if (c < 15) {
      const int key1 = (c + 1) * 64;
      kp0 = *(const half8*)(kb + (size_t)(key1 + srow) * 64 + su);
      kp1 = *(const half8*)(kb + (size_t)(key1 + srow) * 64 + su + 8);
      vp0 = *(const half8*)(vb + (size_t)srow * 1024 + key1 + su);
      vp1 = *(const half8*)(vb + (size_t)srow * 1024 + key1 + su + 8);
    }
    __syncthreads();

    float4v s[2][4];
#pragma unroll
    for (int kt = 0; kt < 4; ++kt) {
      const _Float16* kr = Ks + (kt * 16 + l16) * AST;
      half8 kf0 = *(const half8*)(kr + quad * 8);
      half8 kf1 = *(const half8*)(kr + 32 + quad * 8);
#pragma unroll
      for (int qt = 0; qt < 2; ++qt) {
        float4v a = (float4v)(0.f);
        a = __builtin_amdgcn_mfma_f32_16x16x32_f16(kf0, qf[qt][0], a, 0, 0, 0);
        a = __builtin_amdgcn_mfma_f32_16x16x32_f16(kf1, qf[qt][1], a, 0, 0, 0);
        s[qt][kt] = a;
      }
    }

    float ab[2][4];
#pragma unroll
    for (int qt = 0; qt < 2; ++qt) {
      float mx = fmaxf(fmaxf(fmaxf(s[qt][0][0], s[qt][0][1]), fmaxf(s[qt][0][2], s[qt][0][3])),
                       fmaxf(fmaxf(s[qt][1][0], s[qt][1][1]), fmaxf(s[qt][1][2], s[qt][1][3])));
      mx = fmaxf(mx, fmaxf(fmaxf(fmaxf(s[qt][2][0], s[qt][2][1]), fmaxf(s[qt][2][2], s[qt][2][3])),
                           fmaxf(fmaxf(s[qt][3][0], s[qt][3][1]), fmaxf(s[qt][3][2], s[qt][3][3]))));
      mx = fmaxf(mx, __shfl_xor(mx, 16, 64));
      mx = fmaxf(mx, __shfl_xor(mx, 32, 64));
      const float mn = fmaxf(m_s[qt], mx);
      const float alpha = __expf(m_s[qt] - mn);
      m_s[qt] = mn;
      _Float16* pw = Ps[wave][qt];
      float sum = 0.0f;
#pragma unroll
      for (int kt = 0; kt < 4; ++kt) {
        const float p0 = __expf(s[qt][kt][0] - mn);
        const float p1 = __expf(s[qt][kt][1] - mn);
        const float p2 = __expf(s[qt][kt][2] - mn);
        const float p3 = __expf(s[qt][kt][3] - mn);
        sum += (p0 + p1) + (p2 + p3);
        union { fp16x2 h2[2]; uint2 u; } pk;
        pk.h2[0] = __builtin_amdgcn_cvt_pkrtz(p0, p1);
        pk.h2[1] = __builtin_amdgcn_cvt_pkrtz(p2, p3);
        *(uint2*)(pw + l16 * PST + kt * 16 + quad * 4) = pk.u;
      }
      sum += __shfl_xor(sum, 16, 64);
      sum += __shfl_xor(sum, 32, 64);
      l_s[qt] = l_s[qt] * alpha + sum;
#pragma unroll
      for (int r = 0; r < 4; ++r) ab[qt][r] = __shfl(alpha, quad * 4 + r, 64);
#pragma unroll
      for (int nt = 0; nt < 4; ++nt)
#pragma unroll
        for (int r = 0; r < 4; ++r) acc[qt][nt][r] *= ab[qt][r];
    }

    half8 pf[2][2];
#pragma unroll
    for (int qt = 0; qt < 2; ++qt) {
      const _Float16* pw = Ps[wave][qt];
      pf[qt][0] = *(const half8*)(pw + l16 * PST + quad * 8);
      pf[qt][1] = *(const half8*)(pw + l16 * PST + 32 + quad * 8);
    }
#pragma unroll
    for (int nt = 0; nt < 4; ++nt) {
      const _Float16* vr = Vs + (nt * 16 + l16) * AST;
      half8 vf0 = *(const half8*)(vr + quad * 8);
      half8 vf1 = *(const half8*)(vr + 32 + quad * 8);
#pragma unroll
      for (int qt = 0; qt < 2; ++qt) {
        acc[qt][nt] = __builtin_amdgcn_mfma_f32_16x16x32_f16(pf[qt][0], vf0, acc[qt][nt], 0, 0, 0);
        acc[qt][nt] = __builtin_amdgcn_mfma_f32_16x16x32_f16(pf[qt][1], vf1, acc[qt][nt], 0, 0, 0);
      }
    }
  }

#pragma unroll
  for (int qt = 0; qt < 2; ++qt) {
    const float inv = 1.0f / l_s[qt];
    float ib[4];
#pragma unroll
    for (int r = 0; r < 4; ++r) ib[r] = __shfl(inv, quad * 4 + r, 64);
#pragma unroll
    for (int nt = 0; nt < 4; ++nt) {
#pragma unroll
      for (int r = 0; r < 4; ++r) {
        const int m = q0 + qt * 64 + wave * 16 + quad * 4 + r;
        ao[(size_t)(b * 1024 + m) * 768 + h * 64 + nt * 16 + l16] =
            f2bf(acc[qt][nt][r] * ib[r]);
      }
    }
  }
}

// ---------- out-proj GEMM + bias + residual -> x2 (f32), 128x64 tiles ----------
__global__ void gemm_outproj_kernel(const unsigned short* __restrict__ ao,
                                    const unsigned short* __restrict__ woutt,
                                    const float* __restrict__ b_out,
                                    const float* __restrict__ x,
                                    float* __restrict__ x2) {
  GEMM12864_PROLOGUE(12)
  gemm12864(ao, 768, woutt, 768, 768, row0, col0, As, Bs, acc);
#pragma unroll
  for (int mt = 0; mt < 2; ++mt)
#pragma unroll
    for (int nt = 0; nt < 4; ++nt) {
      const int j = col0 + nt * 16 + l16;
#pragma unroll
      for (int r = 0; r < 4; ++r) {
        const int m = row0 + wave * 32 + mt * 16 + quad * 4 + r;
        const size_t idx = (size_t)m * 768 + j;
        x2[idx] = acc[mt][nt][r] + b_out[j] + x[idx];
      }
    }
}

// ---------- MLP1 GEMM + bias + exact GELU -> h1 (bf16), 128x128 ----------
__global__ void gemm_mlp1_kernel(const unsigned short* __restrict__ h,
                                 const unsigned short* __restrict__ w1t,
                                 const float* __restrict__ b1,
                                 unsigned short* __restrict__ h1) {
  GEMM128_PROLOGUE(24)
  gemm128(h, 768, w1t, 768, 768, row0, col0, As, Bs, acc);
#pragma unroll
  for (int mt = 0; mt < 4; ++mt)
#pragma unroll
    for (int nt = 0; nt < 4; ++nt) {
      const int j = col0 + wc * 64 + nt * 16 + l16;
#pragma unroll
      for (int r = 0; r < 4; ++r) {
        const int m = row0 + wr * 64 + mt * 16 + quad * 4 + r;
        const float y = acc[mt][nt][r] + b1[j];
        const float ge = 0.5f * y * (1.0f + erff(y * 0.70710678118654752f));
        h1[(size_t)m * 3072 + j] = f2bf(ge);
      }
    }
}

// ---------- MLP2 GEMM + bias + residual -> out (f32), 128x64 tiles ----------
__global__ void gemm_mlp2_kernel(const unsigned short* __restrict__ h1,
                                 const unsigned short* __restrict__ w2t,
                                 const float* __restrict__ b2,
                                 const float* __restrict__ x2,
                                 float* __restrict__ out) {
  GEMM12864_PROLOGUE(12)
  gemm12864(h1, 3072, w2t, 3072, 3072, row0, col0, As, Bs, acc);
#pragma unroll
  for (int mt = 0; mt < 2; ++mt)
#pragma unroll
    for (int nt = 0; nt < 4; ++nt) {
      const int j = col0 + nt * 16 + l16;
#pragma unroll
      for (int r = 0; r < 4; ++r) {
        const int m = row0 + wave * 32 + mt * 16 + quad * 4 + r;
        const size_t idx = (size_t)m * 768 + j;
        out[idx] = acc[mt][nt][r] + b2[j] + x2[idx];
      }
    }
}

// ---------- launch ----------
extern "C" void kernel_launch(void* const* d_in, const int* in_sizes, int n_in,
                              void* d_out, int out_size, void* d_ws, size_t ws_size,
                              hipStream_t stream) {
  const float* x       = (const float*)d_in[0];
  const float* q_extra = (const float*)d_in[1];
  const float* ln1_g   = (const float*)d_in[2];
  const float* ln1_b   = (const float*)d_in[3];
  const float* w_kv    = (const float*)d_in[4];
  const float* w_out   = (const float*)d_in[5];
  const float* b_out   = (const float*)d_in[6];
  const float* ln2_g   = (const float*)d_in[7];
  const float* ln2_b   = (const float*)d_in[8];
  const float* w1      = (const float*)d_in[9];
  const float* b1      = (const float*)d_in[10];
  const float* w2      = (const float*)d_in[11];
  const float* b2      = (const float*)d_in[12];
  float* out = (float*)d_out;

  char* ws = (char*)d_ws;
  unsigned short* xn    = (unsigned short*)(ws);
  _Float16*       kbuf  = (_Float16*)(ws + 12582912);
  _Float16*       vtbuf = (_Float16*)(ws + 25165824);
  unsigned short* ao    = (unsigned short*)(ws + 37748736);
  float*          x2    = (float*)(ws + 50331648);
  unsigned short* h1    = (unsigned short*)(ws + 75497472);
  unsigned short* hbuf  = xn;   // xn dead after kv GEMM
  unsigned short* wkvt  = ao;                          // dead before attn writes ao
  unsigned short* woutt = h1;                          // dead before mlp1 writes h1
  unsigned short* w1t   = (unsigned short*)kbuf;       // kbuf dead after attn
  unsigned short* w2t   = (unsigned short*)vtbuf;      // vtbuf dead after attn

  ln_kernel<<<8192, 256, 0, stream>>>(x, ln1_g, ln1_b, xn);
  wtrans_kernel<<<dim3(48, 24), 256, 0, stream>>>(w_kv, wkvt, 768, 1536);
  wtrans_kernel<<<dim3(24, 24), 256, 0, stream>>>(w_out, woutt, 768, 768);
  gemm_kv_kernel<<<768, 256, 0, stream>>>(xn, wkvt, kbuf, vtbuf);
  attn_kernel<<<dim3(8, 12, 8), 256, 0, stream>>>(q_extra, kbuf, vtbuf, ao);
  wtrans_kernel<<<dim3(96, 24), 256, 0, stream>>>(w1, w1t, 768, 3072);
  wtrans_kernel<<<dim3(24, 96), 256, 0, stream>>>(w2, w2t, 3072, 768);
  gemm_outproj_kernel<<<768, 256, 0, stream>>>(ao, woutt, b_out, x, x2);
  ln_kernel<<<8192, 256, 0, stream>>>(x2, ln2_g, ln2_b, hbuf);
  gemm_mlp1_kernel<<<1536, 256, 0, stream>>>(hbuf, w1t, b1, h1);
  gemm_mlp2_kernel<<<768, 256, 0, stream>>>(h1, w2t, b2, x2, out);
}

// Round 9
// 378.250 us; speedup vs baseline: 1.5122x; 1.0302x over previous
//
#include <hip/hip_runtime.h>
#include <math.h>

// ---------- types ----------
typedef __attribute__((ext_vector_type(8))) short short8;
typedef __attribute__((ext_vector_type(8))) _Float16 half8;
typedef __attribute__((ext_vector_type(2))) __fp16 fp16x2;
typedef __attribute__((ext_vector_type(4))) float float4v;

__device__ __forceinline__ unsigned short f2bf(float f) {
  union { unsigned int i; float f; } x; x.f = f;
  unsigned int r = x.i + 0x7fffu + ((x.i >> 16) & 1u);  // round-nearest-even
  return (unsigned short)(r >> 16);
}

// ---------- LayerNorm: one block per row of 768 ----------
__global__ void ln_kernel(const float* __restrict__ in, const float* __restrict__ g,
                          const float* __restrict__ b, unsigned short* __restrict__ out) {
  const int row = blockIdx.x, t = threadIdx.x;
  const float* xr = in + (size_t)row * 768;
  float v0 = xr[t], v1 = xr[t + 256], v2 = xr[t + 512];
  float s = v0 + v1 + v2;
  float s2 = v0 * v0 + v1 * v1 + v2 * v2;
  for (int off = 32; off > 0; off >>= 1) {
    s += __shfl_xor(s, off, 64);
    s2 += __shfl_xor(s2, off, 64);
  }
  __shared__ float red[8];
  const int wave = t >> 6, lane = t & 63;
  if (lane == 0) { red[wave] = s; red[wave + 4] = s2; }
  __syncthreads();
  s = red[0] + red[1] + red[2] + red[3];
  s2 = red[4] + red[5] + red[6] + red[7];
  const float mu = s * (1.0f / 768.0f);
  const float var = s2 * (1.0f / 768.0f) - mu * mu;
  const float rstd = rsqrtf(var + 1e-5f);
  unsigned short* orow = out + (size_t)row * 768;
  orow[t]       = f2bf((v0 - mu) * rstd * g[t]       + b[t]);
  orow[t + 256] = f2bf((v1 - mu) * rstd * g[t + 256] + b[t + 256]);
  orow[t + 512] = f2bf((v2 - mu) * rstd * g[t + 512] + b[t + 512]);
}

// ---------- weight transpose+convert: f32 (K,N) -> bf16 (N,K) ----------
__global__ void wtrans_kernel(const float* __restrict__ in, unsigned short* __restrict__ out,
                              int K, int N) {
  __shared__ float tile[32][33];
  const int k0 = blockIdx.y * 32, n0 = blockIdx.x * 32;
  const int tr = threadIdx.x >> 5, tc = threadIdx.x & 31;
#pragma unroll
  for (int i = 0; i < 4; ++i)
    tile[tr + i * 8][tc] = in[(size_t)(k0 + tr + i * 8) * N + n0 + tc];
  __syncthreads();
#pragma unroll
  for (int i = 0; i < 4; ++i)
    out[(size_t)(n0 + tr + i * 8) * K + k0 + tc] = f2bf(tile[tc][tr + i * 8]);
}

// ---------- XCD-aware block swizzle ----------
#define SWIZ_BLOCK(GX, TW)                                        \
  const int _id = (int)blockIdx.x;                                \
  const int _gy8 = (int)gridDim.x / (8 * (GX));                   \
  const int _xcd = _id & 7, _jj = _id >> 3;                       \
  const int row0 = (_xcd * _gy8 + _jj / (GX)) * 128;              \
  const int col0 = (_jj % (GX)) * (TW);

// ---------- GEMM core 128x128, BK=64, XOR-swizzled LDS ----------
__device__ __forceinline__ void gemm128(
    const unsigned short* __restrict__ A, int lda,
    const unsigned short* __restrict__ Bt, int ldb, int K,
    int row0, int col0,
    unsigned short* As, unsigned short* Bs,
    float4v acc[4][4]) {
  const int t = threadIdx.x, lane = t & 63, wave = t >> 6;
  const int quad = lane >> 4, l16 = lane & 15;
  const int wr = wave >> 1, wc = wave & 1;
  const int srow = lane >> 3;
  const int scol = ((lane & 7) ^ srow) * 8;
#pragma unroll
  for (int mt = 0; mt < 4; ++mt)
#pragma unroll
    for (int nt = 0; nt < 4; ++nt) acc[mt][nt] = (float4v)(0.0f);

  for (int kk = 0; kk < K; kk += 64) {
    __syncthreads();
#pragma unroll
    for (int j = 0; j < 4; ++j) {
      const int chunk = wave * 4 + j;
      const int r = chunk * 8 + srow;
      __builtin_amdgcn_global_load_lds(
          (const __attribute__((address_space(1))) unsigned int*)(A + (size_t)(row0 + r) * lda + kk + scol),
          (__attribute__((address_space(3))) unsigned int*)(As + chunk * 512),
          16, 0, 0);
      __builtin_amdgcn_global_load_lds(
          (const __attribute__((address_space(1))) unsigned int*)(Bt + (size_t)(col0 + r) * ldb + kk + scol),
          (__attribute__((address_space(3))) unsigned int*)(Bs + chunk * 512),
          16, 0, 0);
    }
    __syncthreads();
#pragma unroll
    for (int ks = 0; ks < 2; ++ks) {
      const int gsw = ((ks * 4 + quad) ^ (l16 & 7)) * 8;
      short8 af[4], bfv[4];
#pragma unroll
      for (int i = 0; i < 4; ++i) {
        af[i]  = *(const short8*)(As + (wr * 64 + i * 16 + l16) * 64 + gsw);
        bfv[i] = *(const short8*)(Bs + (wc * 64 + i * 16 + l16) * 64 + gsw);
      }
#pragma unroll
      for (int mt = 0; mt < 4; ++mt)
#pragma unroll
        for (int nt = 0; nt < 4; ++nt)
          acc[mt][nt] = __builtin_amdgcn_mfma_f32_16x16x32_bf16(af[mt], bfv[nt], acc[mt][nt], 0, 0, 0);
    }
  }
}

#define GEMM128_PROLOGUE(GX)                                     \
  __shared__ unsigned short As[128 * 64];                        \
  __shared__ unsigned short Bs[128 * 64];                        \
  float4v acc[4][4];                                             \
  SWIZ_BLOCK(GX, 128)                                            \
  const int t = threadIdx.x, lane = t & 63, wave = t >> 6;       \
  const int quad = lane >> 4, l16 = lane & 15;                   \
  const int wr = wave >> 1, wc = wave & 1; (void)t;

// ---------- GEMM core 128x64, BK=64, XOR-swizzled LDS ----------
__device__ __forceinline__ void gemm12864(
    const unsigned short* __restrict__ A, int lda,
    const unsigned short* __restrict__ Bt, int ldb, int K,
    int row0, int col0,
    unsigned short* As, unsigned short* Bs,
    float4v acc[2][4]) {
  const int t = threadIdx.x, lane = t & 63, wave = t >> 6;
  const int quad = lane >> 4, l16 = lane & 15;
  const int srow = lane >> 3;
  const int scol = ((lane & 7) ^ srow) * 8;
#pragma unroll
  for (int mt = 0; mt < 2; ++mt)
#pragma unroll
    for (int nt = 0; nt < 4; ++nt) acc[mt][nt] = (float4v)(0.0f);

  for (int kk = 0; kk < K; kk += 64) {
    __syncthreads();
#pragma unroll
    for (int j = 0; j < 4; ++j) {
      const int chunk = wave * 4 + j;
      const int r = chunk * 8 + srow;
      __builtin_amdgcn_global_load_lds(
          (const __attribute__((address_space(1))) unsigned int*)(A + (size_t)(row0 + r) * lda + kk + scol),
          (__attribute__((address_space(3))) unsigned int*)(As + chunk * 512),
          16, 0, 0);
    }
#pragma unroll
    for (int j = 0; j < 2; ++j) {
      const int chunk = wave * 2 + j;
      const int r = chunk * 8 + srow;
      __builtin_amdgcn_global_load_lds(
          (const __attribute__((address_space(1))) unsigned int*)(Bt + (size_t)(col0 + r) * ldb + kk + scol),
          (__attribute__((address_space(3))) unsigned int*)(Bs + chunk * 512),
          16, 0, 0);
    }
    __syncthreads();
#pragma unroll
    for (int ks = 0; ks < 2; ++ks) {
      const int gsw = ((ks * 4 + quad) ^ (l16 & 7)) * 8;
      short8 af[2], bfv[4];
#pragma unroll
      for (int i = 0; i < 2; ++i)
        af[i] = *(const short8*)(As + (wave * 32 + i * 16 + l16) * 64 + gsw);
#pragma unroll
      for (int i = 0; i < 4; ++i)
        bfv[i] = *(const short8*)(Bs + (i * 16 + l16) * 64 + gsw);
#pragma unroll
      for (int mt = 0; mt < 2; ++mt)
#pragma unroll
        for (int nt = 0; nt < 4; ++nt)
          acc[mt][nt] = __builtin_amdgcn_mfma_f32_16x16x32_bf16(af[mt], bfv[nt], acc[mt][nt], 0, 0, 0);
    }
  }
}

#define GEMM12864_PROLOGUE(GX)                                   \
  __shared__ unsigned short As[128 * 64];                        \
  __shared__ unsigned short Bs[64 * 64];                         \
  float4v acc[2][4];                                             \
  SWIZ_BLOCK(GX, 64)                                             \
  const int t = threadIdx.x, lane = t & 63, wave = t >> 6;       \
  const int quad = lane >> 4, l16 = lane & 15; (void)t;

// ---------- kv GEMM: xn @ w_kv -> k (B,H,N,DH) f16, v^T (B,H,DH,N) f16 ----------
__global__ void gemm_kv_kernel(const unsigned short* __restrict__ xn,
                               const unsigned short* __restrict__ wkvt,
                               _Float16* __restrict__ kbuf,
                               _Float16* __restrict__ vtbuf) {
  GEMM128_PROLOGUE(12)
  gemm128(xn, 768, wkvt, 768, 768, row0, col0, As, Bs, acc);
#pragma unroll
  for (int mt = 0; mt < 4; ++mt)
#pragma unroll
    for (int nt = 0; nt < 4; ++nt) {
      const int j = col0 + wc * 64 + nt * 16 + l16;
#pragma unroll
      for (int r = 0; r < 4; ++r) {
        const int m = row0 + wr * 64 + mt * 16 + quad * 4 + r;
        const int bb = m >> 10, n = m & 1023;
        const float c = acc[mt][nt][r];
        if (j < 768) {
          const int hh = j >> 6, d = j & 63;
          kbuf[((size_t)(bb * 12 + hh) * 1024 + n) * 64 + d] = (_Float16)c;
        } else {
          const int j2 = j - 768, hh = j2 >> 6, d = j2 & 63;
          vtbuf[((size_t)(bb * 12 + hh) * 64 + d) * 1024 + n] = (_Float16)c;
        }
      }
    }
}

// ---------- MFMA flash attention, f16 ----------
// 1536 blocks, 1D: id = qb*96 + (h*8+b); id%8 = b -> all q-blocks of one (b,h)
// (and all heads of one batch) share an XCD -> K/V stays in that XCD's L2.
// Block = 64 q rows, 4 waves x 16 q rows. Key chunks of 64 staged in LDS,
// register prefetch of chunk c+1 overlaps compute. exp2-domain softmax:
// Q pre-scaled by 0.125*log2(e) so exp() is a bare v_exp_f32 (exp2f).
#define AST 72
#define PST 72
__global__ void attn_kernel(const float* __restrict__ q_extra,
                            const _Float16* __restrict__ kbuf,
                            const _Float16* __restrict__ vtbuf,
                            unsigned short* __restrict__ ao) {
  __shared__ _Float16 Ks[64 * AST];
  __shared__ _Float16 Vs[64 * AST];
  __shared__ _Float16 Ps[4][16 * PST];
  const int id = (int)blockIdx.x;
  const int pair = id % 96, qb = id / 96;
  const int h = pair >> 3, b = pair & 7;
  const int q0 = qb * 64;
  const int t = threadIdx.x, lane = t & 63, wave = t >> 6;
  const int quad = lane >> 4, l16 = lane & 15;

  // Q fragments (B-operand layout) f16, pre-scaled by 0.125*log2(e)
  const float QS = 0.125f * 1.44269504088896f;
  half8 qf0, qf1;
  {
    const float* qp = q_extra +
        ((size_t)((b * 1024 + q0 + wave * 16 + l16) * 12 + h)) * 64 + quad * 8;
    float4 a0 = *(const float4*)(qp);
    float4 a1 = *(const float4*)(qp + 4);
    float4 c0 = *(const float4*)(qp + 32);
    float4 c1 = *(const float4*)(qp + 36);
    union { fp16x2 h2[4]; half8 h8; } u0, u1;
    u0.h2[0] = __builtin_amdgcn_cvt_pkrtz(a0.x * QS, a0.y * QS);
    u0.h2[1] = __builtin_amdgcn_cvt_pkrtz(a0.z * QS, a0.w * QS);
    u0.h2[2] = __builtin_amdgcn_cvt_pkrtz(a1.x * QS, a1.y * QS);
    u0.h2[3] = __builtin_amdgcn_cvt_pkrtz(a1.z * QS, a1.w * QS);
    u1.h2[0] = __builtin_amdgcn_cvt_pkrtz(c0.x * QS, c0.y * QS);
    u1.h2[1] = __builtin_amdgcn_cvt_pkrtz(c0.z * QS, c0.w * QS);
    u1.h2[2] = __builtin_amdgcn_cvt_pkrtz(c1.x * QS, c1.y * QS);
    u1.h2[3] = __builtin_amdgcn_cvt_pkrtz(c1.z * QS, c1.w * QS);
    qf0 = u0.h8; qf1 = u1.h8;
  }

  const _Float16* kb = kbuf + (size_t)(b * 12 + h) * 65536;
  const _Float16* vb = vtbuf + (size_t)(b * 12 + h) * 65536;
  const int srow = t >> 2, su = (t & 3) * 16;

  // prefetch chunk 0
  half8 kp0 = *(const half8*)(kb + (size_t)srow * 64 + su);
  half8 kp1 = *(const half8*)(kb + (size_t)srow * 64 + su + 8);
  half8 vp0 = *(const half8*)(vb + (size_t)srow * 1024 + su);
  half8 vp1 = *(const half8*)(vb + (size_t)srow * 1024 + su + 8);

  float m_s = -1e30f, l_s = 0.0f;
  float4v acc[4];
  acc[0] = (float4v)(0.f); acc[1] = (float4v)(0.f);
  acc[2] = (float4v)(0.f); acc[3] = (float4v)(0.f);
  _Float16* pw = Ps[wave];

  for (int c = 0; c < 16; ++c) {
    __syncthreads();
    *(half8*)(Ks + srow * AST + su)     = kp0;
    *(half8*)(Ks + srow * AST + su + 8) = kp1;
    *(half8*)(Vs + srow * AST + su)     = vp0;
    *(half8*)(Vs + srow * AST + su + 8) = vp1;
    if (c < 15) {
      const int key1 = (c + 1) * 64;
      kp0 = *(const half8*)(kb + (size_t)(key1 + srow) * 64 + su);
      kp1 = *(const half8*)(kb + (size_t)(key1 + srow) * 64 + su + 8);
      vp0 = *(const half8*)(vb + (size_t)srow * 1024 + key1 + su);
      vp1 = *(const half8*)(vb + (size_t)srow * 1024 + key1 + su + 8);
    }
    __syncthreads();

    // S^T = K @ Q^T (log2-domain scores)
    float4v s[4];
#pragma unroll
    for (int kt = 0; kt < 4; ++kt) {
      const _Float16* kr = Ks + (kt * 16 + l16) * AST;
      half8 kf0 = *(const half8*)(kr + quad * 8);
      half8 kf1 = *(const half8*)(kr + 32 + quad * 8);
      float4v a = (float4v)(0.f);
      a = __builtin_amdgcn_mfma_f32_16x16x32_f16(kf0, qf0, a, 0, 0, 0);
      a = __builtin_amdgcn_mfma_f32_16x16x32_f16(kf1, qf1, a, 0, 0, 0);
      s[kt] = a;
    }

    // per-lane online softmax (base-2) for q = l16
    float mx = fmaxf(fmaxf(fmaxf(s[0][0], s[0][1]), fmaxf(s[0][2], s[0][3])),
                     fmaxf(fmaxf(s[1][0], s[1][1]), fmaxf(s[1][2], s[1][3])));
    mx = fmaxf(mx, fmaxf(fmaxf(fmaxf(s[2][0], s[2][1]), fmaxf(s[2][2], s[2][3])),
                         fmaxf(fmaxf(s[3][0], s[3][1]), fmaxf(s[3][2], s[3][3]))));
    mx = fmaxf(mx, __shfl_xor(mx, 16, 64));
    mx = fmaxf(mx, __shfl_xor(mx, 32, 64));
    const float mn = fmaxf(m_s, mx);
    const float alpha = exp2f(m_s - mn);
    m_s = mn;

    float sum = 0.0f;
#pragma unroll
    for (int kt = 0; kt < 4; ++kt) {
      const float p0 = exp2f(s[kt][0] - mn);
      const float p1 = exp2f(s[kt][1] - mn);
      const float p2 = exp2f(s[kt][2] - mn);
      const float p3 = exp2f(s[kt][3] - mn);
      sum += (p0 + p1) + (p2 + p3);
      union { fp16x2 h2[2]; uint2 u; } pk;
      pk.h2[0] = __builtin_amdgcn_cvt_pkrtz(p0, p1);
      pk.h2[1] = __builtin_amdgcn_cvt_pkrtz(p2, p3);
      *(uint2*)(pw + l16 * PST + kt * 16 + quad * 4) = pk.u;
    }
    sum += __shfl_xor(sum, 16, 64);
    sum += __shfl_xor(sum, 32, 64);
    l_s = l_s * alpha + sum;

    float ab[4];
#pragma unroll
    for (int r = 0; r < 4; ++r) ab[r] = __shfl(alpha, quad * 4 + r, 64);
#pragma unroll
    for (int nt = 0; nt < 4; ++nt)
#pragma unroll
      for (int r = 0; r < 4; ++r) acc[nt][r] *= ab[r];

    // O += P @ V
    half8 pf0 = *(const half8*)(pw + l16 * PST + quad * 8);
    half8 pf1 = *(const half8*)(pw + l16 * PST + 32 + quad * 8);
#pragma unroll
    for (int nt = 0; nt < 4; ++nt) {
      const _Float16* vr = Vs + (nt * 16 + l16) * AST;
      half8 vf0 = *(const half8*)(vr + quad * 8);
      half8 vf1 = *(const half8*)(vr + 32 + quad * 8);
      acc[nt] = __builtin_amdgcn_mfma_f32_16x16x32_f16(pf0, vf0, acc[nt], 0, 0, 0);
      acc[nt] = __builtin_amdgcn_mfma_f32_16x16x32_f16(pf1, vf1, acc[nt], 0, 0, 0);
    }
  }

  const float inv = 1.0f / l_s;
  float ib[4];
#pragma unroll
  for (int r = 0; r < 4; ++r) ib[r] = __shfl(inv, quad * 4 + r, 64);
#pragma unroll
  for (int nt = 0; nt < 4; ++nt) {
#pragma unroll
    for (int r = 0; r < 4; ++r) {
      const int m = q0 + wave * 16 + quad * 4 + r;
      ao[(size_t)(b * 1024 + m) * 768 + h * 64 + nt * 16 + l16] =
          f2bf(acc[nt][r] * ib[r]);
    }
  }
}

// ---------- out-proj GEMM + bias + residual -> x2 (f32), 128x64 tiles ----------
__global__ void gemm_outproj_kernel(const unsigned short* __restrict__ ao,
                                    const unsigned short* __restrict__ woutt,
                                    const float* __restrict__ b_out,
                                    const float* __restrict__ x,
                                    float* __restrict__ x2) {
  GEMM12864_PROLOGUE(12)
  gemm12864(ao, 768, woutt, 768, 768, row0, col0, As, Bs, acc);
#pragma unroll
  for (int mt = 0; mt < 2; ++mt)
#pragma unroll
    for (int nt = 0; nt < 4; ++nt) {
      const int j = col0 + nt * 16 + l16;
#pragma unroll
      for (int r = 0; r < 4; ++r) {
        const int m = row0 + wave * 32 + mt * 16 + quad * 4 + r;
        const size_t idx = (size_t)m * 768 + j;
        x2[idx] = acc[mt][nt][r] + b_out[j] + x[idx];
      }
    }
}

// ---------- MLP1 GEMM + bias + exact GELU -> h1 (bf16), 128x128 ----------
__global__ void gemm_mlp1_kernel(const unsigned short* __restrict__ h,
                                 const unsigned short* __restrict__ w1t,
                                 const float* __restrict__ b1,
                                 unsigned short* __restrict__ h1) {
  GEMM128_PROLOGUE(24)
  gemm128(h, 768, w1t, 768, 768, row0, col0, As, Bs, acc);
#pragma unroll
  for (int mt = 0; mt < 4; ++mt)
#pragma unroll
    for (int nt = 0; nt < 4; ++nt) {
      const int j = col0 + wc * 64 + nt * 16 + l16;
#pragma unroll
      for (int r = 0; r < 4; ++r) {
        const int m = row0 + wr * 64 + mt * 16 + quad * 4 + r;
        const float y = acc[mt][nt][r] + b1[j];
        const float ge = 0.5f * y * (1.0f + erff(y * 0.70710678118654752f));
        h1[(size_t)m * 3072 + j] = f2bf(ge);
      }
    }
}

// ---------- MLP2 GEMM + bias + residual -> out (f32), 128x64 tiles ----------
__global__ void gemm_mlp2_kernel(const unsigned short* __restrict__ h1,
                                 const unsigned short* __restrict__ w2t,
                                 const float* __restrict__ b2,
                                 const float* __restrict__ x2,
                                 float* __restrict__ out) {
  GEMM12864_PROLOGUE(12)
  gemm12864(h1, 3072, w2t, 3072, 3072, row0, col0, As, Bs, acc);
#pragma unroll
  for (int mt = 0; mt < 2; ++mt)
#pragma unroll
    for (int nt = 0; nt < 4; ++nt) {
      const int j = col0 + nt * 16 + l16;
#pragma unroll
      for (int r = 0; r < 4; ++r) {
        const int m = row0 + wave * 32 + mt * 16 + quad * 4 + r;
        const size_t idx = (size_t)m * 768 + j;
        out[idx] = acc[mt][nt][r] + b2[j] + x2[idx];
      }
    }
}

// ---------- launch ----------
extern "C" void kernel_launch(void* const* d_in, const int* in_sizes, int n_in,
                              void* d_out, int out_size, void* d_ws, size_t ws_size,
                              hipStream_t stream) {
  const float* x       = (const float*)d_in[0];
  const float* q_extra = (const float*)d_in[1];
  const float* ln1_g   = (const float*)d_in[2];
  const float* ln1_b   = (const float*)d_in[3];
  const float* w_kv    = (const float*)d_in[4];
  const float* w_out   = (const float*)d_in[5];
  const float* b_out   = (const float*)d_in[6];
  const float* ln2_g   = (const float*)d_in[7];
  const float* ln2_b   = (const float*)d_in[8];
  const float* w1      = (const float*)d_in[9];
  const float* b1      = (const float*)d_in[10];
  const float* w2      = (const float*)d_in[11];
  const float* b2      = (const float*)d_in[12];
  float* out = (float*)d_out;

  char* ws = (char*)d_ws;
  unsigned short* xn    = (unsigned short*)(ws);
  _Float16*       kbuf  = (_Float16*)(ws + 12582912);
  _Float16*       vtbuf = (_Float16*)(ws + 25165824);
  unsigned short* ao    = (unsigned short*)(ws + 37748736);
  float*          x2    = (float*)(ws + 50331648);
  unsigned short* h1    = (unsigned short*)(ws + 75497472);
  unsigned short* hbuf  = xn;   // xn dead after kv GEMM
  unsigned short* wkvt  = ao;                          // dead before attn writes ao
  unsigned short* woutt = h1;                          // dead before mlp1 writes h1
  unsigned short* w1t   = (unsigned short*)kbuf;       // kbuf dead after attn
  unsigned short* w2t   = (unsigned short*)vtbuf;      // vtbuf dead after attn

  ln_kernel<<<8192, 256, 0, stream>>>(x, ln1_g, ln1_b, xn);
  wtrans_kernel<<<dim3(48, 24), 256, 0, stream>>>(w_kv, wkvt, 768, 1536);
  wtrans_kernel<<<dim3(24, 24), 256, 0, stream>>>(w_out, woutt, 768, 768);
  gemm_kv_kernel<<<768, 256, 0, stream>>>(xn, wkvt, kbuf, vtbuf);
  attn_kernel<<<1536, 256, 0, stream>>>(q_extra, kbuf, vtbuf, ao);
  wtrans_kernel<<<dim3(96, 24), 256, 0, stream>>>(w1, w1t, 768, 3072);
  wtrans_kernel<<<dim3(24, 96), 256, 0, stream>>>(w2, w2t, 3072, 768);
  gemm_outproj_kernel<<<768, 256, 0, stream>>>(ao, woutt, b_out, x, x2);
  ln_kernel<<<8192, 256, 0, stream>>>(x2, ln2_g, ln2_b, hbuf);
  gemm_mlp1_kernel<<<1536, 256, 0, stream>>>(hbuf, w1t, b1, h1);
  gemm_mlp2_kernel<<<768, 256, 0, stream>>>(h1, w2t, b2, x2, out);
}